// Round 4
// baseline (353.558 us; speedup 1.0000x reference)
//
#include <hip/hip_runtime.h>
#include <math.h>

#define CUTOFF_F 5.0f
#define MIN_DIST_F 0.01f
#define EPS_D 1e-7

typedef float f32x4 __attribute__((ext_vector_type(4)));

static __device__ __forceinline__ void nt_store4(float* p, float a, float b, float c, float d) {
    f32x4 v = {a, b, c, d};
    __builtin_nontemporal_store(v, reinterpret_cast<f32x4*>(p));
}

// ---------------------------------------------------------------------------
// Prep: per-system 3x3 inverse (double), wrapped positions, cartesian shifts.
// wp[b*N+n][3] (f32), sc[b*27+s][3] (f32) into workspace.
// ---------------------------------------------------------------------------
__global__ void bnl_prep(const float* __restrict__ pos,
                         const float* __restrict__ cell,
                         float* __restrict__ wp,
                         float* __restrict__ sc,
                         int B, int N) {
    int tid = blockIdx.x * blockDim.x + threadIdx.x;
    int nthreads = gridDim.x * blockDim.x;

    for (int t = tid; t < B * 27; t += nthreads) {
        int b = t / 27, s = t - b * 27;
        int sx = s / 9 - 1;
        int sy = (s / 3) % 3 - 1;
        int sz = s - (s / 3) * 3 - 1;
        const float* c = cell + b * 9;
        sc[t * 3 + 0] = (float)((double)sx * c[0] + (double)sy * c[3] + (double)sz * c[6]);
        sc[t * 3 + 1] = (float)((double)sx * c[1] + (double)sy * c[4] + (double)sz * c[7]);
        sc[t * 3 + 2] = (float)((double)sx * c[2] + (double)sy * c[5] + (double)sz * c[8]);
    }

    int total = B * N;
    for (int n = tid; n < total; n += nthreads) {
        int b = n / N;
        const float* c = cell + b * 9;
        double a00 = c[0], a01 = c[1], a02 = c[2];
        double a10 = c[3], a11 = c[4], a12 = c[5];
        double a20 = c[6], a21 = c[7], a22 = c[8];
        double co00 =  (a11 * a22 - a12 * a21);
        double co01 = -(a10 * a22 - a12 * a20);
        double co02 =  (a10 * a21 - a11 * a20);
        double det = a00 * co00 + a01 * co01 + a02 * co02;
        double id = 1.0 / det;
        double m00 = co00 * id;
        double m01 = -(a01 * a22 - a02 * a21) * id;
        double m02 =  (a01 * a12 - a02 * a11) * id;
        double m10 = co01 * id;
        double m11 =  (a00 * a22 - a02 * a20) * id;
        double m12 = -(a00 * a12 - a02 * a10) * id;
        double m20 = co02 * id;
        double m21 = -(a00 * a21 - a01 * a20) * id;
        double m22 =  (a00 * a11 - a01 * a10) * id;

        double p0 = pos[n * 3 + 0], p1 = pos[n * 3 + 1], p2 = pos[n * 3 + 2];
        double s0 = p0 * m00 + p1 * m10 + p2 * m20 + EPS_D;
        double s1 = p0 * m01 + p1 * m11 + p2 * m21 + EPS_D;
        double s2 = p0 * m02 + p1 * m12 + p2 * m22 + EPS_D;
        s0 -= floor(s0); s1 -= floor(s1); s2 -= floor(s2);
        s0 -= EPS_D; s1 -= EPS_D; s2 -= EPS_D;
        wp[n * 3 + 0] = (float)(s0 * a00 + s1 * a10 + s2 * a20);
        wp[n * 3 + 1] = (float)(s0 * a01 + s1 * a11 + s2 * a21);
        wp[n * 3 + 2] = (float)(s0 * a02 + s1 * a12 + s2 * a22);
    }
}

// ---------------------------------------------------------------------------
// Fill, half-row blocks: block = (b, i, half). Stage wp[b, half*N/2 .. ) and
// sc[b] in LDS (3.4 KB). Each lane owns 4 consecutive pairs, computes the
// geometry ONCE per pair, and streams diff (3x float4), dist, mask with
// nontemporal float4 stores. Output: [diff 3*D1][dist D1][mask D1].
// ---------------------------------------------------------------------------
__global__ __launch_bounds__(256) void bnl_fill3(const float* __restrict__ wp,
                                                 const float* __restrict__ sc,
                                                 float* __restrict__ out,
                                                 int B, int N) {
    extern __shared__ float lds[];          // [(N/2)*3] wp half-row, then [81] sc
    const int Nh = N >> 1;
    float* lwp = lds;
    float* lsc = lds + Nh * 3;

    int blk  = blockIdx.x;
    int b    = blk / (N * 2);
    int rem  = blk - b * (N * 2);
    int i    = rem >> 1;
    int half = rem & 1;
    int jbase = half * Nh;

    const float* wrow = wp + ((size_t)b * N + jbase) * 3;
    int nf4 = (Nh * 3) >> 2;
    for (int t = threadIdx.x; t < nf4; t += blockDim.x)
        reinterpret_cast<f32x4*>(lwp)[t] = reinterpret_cast<const f32x4*>(wrow)[t];
    for (int t = (nf4 << 2) + threadIdx.x; t < Nh * 3; t += blockDim.x)
        lwp[t] = wrow[t];
    for (int t = threadIdx.x; t < 81; t += blockDim.x)
        lsc[t] = sc[(size_t)b * 81 + t];
    __syncthreads();

    const float* pip = wp + ((size_t)b * N + i) * 3;
    float pix = pip[0], piy = pip[1], piz = pip[2];

    size_t D1   = (size_t)B * N * N * 27;
    size_t NPh  = (size_t)Nh * 27;                        // pairs per half-row
    size_t base = (size_t)(b * N + i) * N * 27 + (size_t)half * NPh;
    float* diff_out = out + base * 3;
    float* dist_out = out + 3 * D1 + base;
    float* mask_out = out + 4 * D1 + base;

    int NQ = (int)(NPh >> 2);                             // quads

    for (int q = threadIdx.x; q < NQ; q += blockDim.x) {
        float dv[12], tv[4], mv[4];
        int p0 = q << 2;
        unsigned j = (unsigned)p0 / 27u;
        unsigned s = (unsigned)p0 - j * 27u;
#pragma unroll
        for (int k = 0; k < 4; ++k) {
            float dx = lwp[j * 3 + 0] + lsc[s * 3 + 0] - pix;
            float dy = lwp[j * 3 + 1] + lsc[s * 3 + 1] - piy;
            float dz = lwp[j * 3 + 2] + lsc[s * 3 + 2] - piz;
            float dist = sqrtf(dx * dx + dy * dy + dz * dz);
            bool m = (dist < CUTOFF_F) && (dist > MIN_DIST_F);
            dv[k * 3 + 0] = m ? dx : 0.0f;
            dv[k * 3 + 1] = m ? dy : 0.0f;
            dv[k * 3 + 2] = m ? dz : 0.0f;
            tv[k] = m ? dist : 0.0f;
            mv[k] = m ? 1.0f : 0.0f;
            ++s;
            if (s == 27u) { s = 0u; ++j; }
        }
        float* dp = diff_out + (size_t)p0 * 3;
        nt_store4(dp + 0, dv[0], dv[1], dv[2],  dv[3]);
        nt_store4(dp + 4, dv[4], dv[5], dv[6],  dv[7]);
        nt_store4(dp + 8, dv[8], dv[9], dv[10], dv[11]);
        nt_store4(dist_out + p0, tv[0], tv[1], tv[2], tv[3]);
        nt_store4(mask_out + p0, mv[0], mv[1], mv[2], mv[3]);
    }
}

extern "C" void kernel_launch(void* const* d_in, const int* in_sizes, int n_in,
                              void* d_out, int out_size, void* d_ws, size_t ws_size,
                              hipStream_t stream) {
    const float* pos  = (const float*)d_in[0];   // [B*N,3]
    const float* cell = (const float*)d_in[1];   // [B,3,3]
    int B = in_sizes[1] / 9;
    int N = in_sizes[0] / (3 * B);

    float* wp = (float*)d_ws;                    // B*N*3 floats
    float* sc = wp + (size_t)B * N * 3;          // B*27*3 floats

    bnl_prep<<<32, 256, 0, stream>>>(pos, cell, wp, sc, B, N);

    size_t lds_bytes = ((size_t)(N / 2) * 3 + 81) * sizeof(float);
    bnl_fill3<<<B * N * 2, 256, lds_bytes, stream>>>(wp, sc, (float*)d_out, B, N);
}

// Round 5
// 116.392 us; speedup vs baseline: 3.0376x; 3.0376x over previous
//
#include <hip/hip_runtime.h>
#include <math.h>

#define CUTOFF_F 5.0f
#define MIN_DIST_F 0.01f
#define EPS_D 1e-7

typedef float f32x4 __attribute__((ext_vector_type(4)));

// ---------------------------------------------------------------------------
// Prep: per-system 3x3 inverse (double), wrapped positions, cartesian shifts.
// wp[b*N+n][3] (f32), sc[b*27+s][3] (f32) into workspace.
// ---------------------------------------------------------------------------
__global__ void bnl_prep(const float* __restrict__ pos,
                         const float* __restrict__ cell,
                         float* __restrict__ wp,
                         float* __restrict__ sc,
                         int B, int N) {
    int tid = blockIdx.x * blockDim.x + threadIdx.x;
    int nthreads = gridDim.x * blockDim.x;

    for (int t = tid; t < B * 27; t += nthreads) {
        int b = t / 27, s = t - b * 27;
        int sx = s / 9 - 1;
        int sy = (s / 3) % 3 - 1;
        int sz = s - (s / 3) * 3 - 1;
        const float* c = cell + b * 9;
        sc[t * 3 + 0] = (float)((double)sx * c[0] + (double)sy * c[3] + (double)sz * c[6]);
        sc[t * 3 + 1] = (float)((double)sx * c[1] + (double)sy * c[4] + (double)sz * c[7]);
        sc[t * 3 + 2] = (float)((double)sx * c[2] + (double)sy * c[5] + (double)sz * c[8]);
    }

    int total = B * N;
    for (int n = tid; n < total; n += nthreads) {
        int b = n / N;
        const float* c = cell + b * 9;
        double a00 = c[0], a01 = c[1], a02 = c[2];
        double a10 = c[3], a11 = c[4], a12 = c[5];
        double a20 = c[6], a21 = c[7], a22 = c[8];
        double co00 =  (a11 * a22 - a12 * a21);
        double co01 = -(a10 * a22 - a12 * a20);
        double co02 =  (a10 * a21 - a11 * a20);
        double det = a00 * co00 + a01 * co01 + a02 * co02;
        double id = 1.0 / det;
        double m00 = co00 * id;
        double m01 = -(a01 * a22 - a02 * a21) * id;
        double m02 =  (a01 * a12 - a02 * a11) * id;
        double m10 = co01 * id;
        double m11 =  (a00 * a22 - a02 * a20) * id;
        double m12 = -(a00 * a12 - a02 * a10) * id;
        double m20 = co02 * id;
        double m21 = -(a00 * a21 - a01 * a20) * id;
        double m22 =  (a00 * a11 - a01 * a10) * id;

        double p0 = pos[n * 3 + 0], p1 = pos[n * 3 + 1], p2 = pos[n * 3 + 2];
        double s0 = p0 * m00 + p1 * m10 + p2 * m20 + EPS_D;
        double s1 = p0 * m01 + p1 * m11 + p2 * m21 + EPS_D;
        double s2 = p0 * m02 + p1 * m12 + p2 * m22 + EPS_D;
        s0 -= floor(s0); s1 -= floor(s1); s2 -= floor(s2);
        s0 -= EPS_D; s1 -= EPS_D; s2 -= EPS_D;
        wp[n * 3 + 0] = (float)(s0 * a00 + s1 * a10 + s2 * a20);
        wp[n * 3 + 1] = (float)(s0 * a01 + s1 * a11 + s2 * a21);
        wp[n * 3 + 2] = (float)(s0 * a02 + s1 * a12 + s2 * a22);
    }
}

// ---------------------------------------------------------------------------
// Fill, half-row blocks + LDS diff-transpose: block = (b, i, half).
// Stage wp[b, half*N/2..) + sc[b] in LDS. Each thread computes 4 consecutive
// pairs; diff (12 floats/thread) goes through an LDS tile so ALL global
// stores are contiguous wave-wide dwordx4 bursts. Plain (cached) stores —
// NT stores caused 2x write amplification on strided data (round 4).
// Output: [diff 3*D1][dist D1][mask D1], D1 = B*N*N*27.
// ---------------------------------------------------------------------------
__global__ __launch_bounds__(256) void bnl_fill4(const float* __restrict__ wp,
                                                 const float* __restrict__ sc,
                                                 float* __restrict__ out,
                                                 int B, int N) {
    extern __shared__ float lds[];
    const int Nh = N >> 1;
    float* lwp = lds;                       // Nh*3
    float* lsc = lwp + Nh * 3;              // 81
    int off = Nh * 3 + 81;
    off = (off + 3) & ~3;                   // 16B-align the diff tile
    f32x4* ldiff = reinterpret_cast<f32x4*>(lds + off);  // 256*3 float4s

    int blk  = blockIdx.x;
    int b    = blk / (N * 2);
    int rem  = blk - b * (N * 2);
    int i    = rem >> 1;
    int half = rem & 1;
    int jbase = half * Nh;

    const float* wrow = wp + ((size_t)b * N + jbase) * 3;
    int nf4s = (Nh * 3) >> 2;
    for (int t = threadIdx.x; t < nf4s; t += blockDim.x)
        reinterpret_cast<f32x4*>(lwp)[t] = reinterpret_cast<const f32x4*>(wrow)[t];
    for (int t = (nf4s << 2) + threadIdx.x; t < Nh * 3; t += blockDim.x)
        lwp[t] = wrow[t];
    for (int t = threadIdx.x; t < 81; t += blockDim.x)
        lsc[t] = sc[(size_t)b * 81 + t];
    __syncthreads();

    const float* pip = wp + ((size_t)b * N + i) * 3;
    float pix = pip[0], piy = pip[1], piz = pip[2];

    size_t D1   = (size_t)B * N * N * 27;
    size_t NPh  = (size_t)Nh * 27;                        // pairs per half-row
    size_t base = (size_t)(b * N + i) * N * 27 + (size_t)half * NPh;
    float* diff_out = out + base * 3;
    float* dist_out = out + 3 * D1 + base;
    float* mask_out = out + 4 * D1 + base;

    int NQ = (int)(NPh >> 2);                             // quads (N%8==0)
    int BD = blockDim.x;

    for (int q0 = 0; q0 < NQ; q0 += BD) {
        int q = q0 + threadIdx.x;
        if (q < NQ) {
            float dv[12], tv[4], mv[4];
            int p0 = q << 2;
            unsigned j = (unsigned)p0 / 27u;
            unsigned s = (unsigned)p0 - j * 27u;
#pragma unroll
            for (int k = 0; k < 4; ++k) {
                float dx = lwp[j * 3 + 0] + lsc[s * 3 + 0] - pix;
                float dy = lwp[j * 3 + 1] + lsc[s * 3 + 1] - piy;
                float dz = lwp[j * 3 + 2] + lsc[s * 3 + 2] - piz;
                float dist = sqrtf(dx * dx + dy * dy + dz * dz);
                bool m = (dist < CUTOFF_F) && (dist > MIN_DIST_F);
                dv[k * 3 + 0] = m ? dx : 0.0f;
                dv[k * 3 + 1] = m ? dy : 0.0f;
                dv[k * 3 + 2] = m ? dz : 0.0f;
                tv[k] = m ? dist : 0.0f;
                mv[k] = m ? 1.0f : 0.0f;
                ++s;
                if (s == 27u) { s = 0u; ++j; }
            }
            // diff -> LDS, linear layout: thread t owns float4 slots 3t..3t+2
            // (48B lane stride: 8 consecutive lanes cover all 32 banks -> no conflict)
            int t3 = threadIdx.x * 3;
            ldiff[t3 + 0] = (f32x4){dv[0], dv[1], dv[2],  dv[3]};
            ldiff[t3 + 1] = (f32x4){dv[4], dv[5], dv[6],  dv[7]};
            ldiff[t3 + 2] = (f32x4){dv[8], dv[9], dv[10], dv[11]};
            // dist/mask already contiguous across threads -> direct store
            *reinterpret_cast<f32x4*>(dist_out + (size_t)q * 4) =
                (f32x4){tv[0], tv[1], tv[2], tv[3]};
            *reinterpret_cast<f32x4*>(mask_out + (size_t)q * 4) =
                (f32x4){mv[0], mv[1], mv[2], mv[3]};
        }
        __syncthreads();
        // stream the diff tile out: consecutive float4s per consecutive thread
        int nq  = NQ - q0; if (nq > BD) nq = BD;
        int nf4 = nq * 3;
        f32x4* gdiff4 = reinterpret_cast<f32x4*>(diff_out + (size_t)q0 * 12);
        for (int f = threadIdx.x; f < nf4; f += BD)
            gdiff4[f] = ldiff[f];
        __syncthreads();
    }
}

extern "C" void kernel_launch(void* const* d_in, const int* in_sizes, int n_in,
                              void* d_out, int out_size, void* d_ws, size_t ws_size,
                              hipStream_t stream) {
    const float* pos  = (const float*)d_in[0];   // [B*N,3]
    const float* cell = (const float*)d_in[1];   // [B,3,3]
    int B = in_sizes[1] / 9;
    int N = in_sizes[0] / (3 * B);

    float* wp = (float*)d_ws;                    // B*N*3 floats
    float* sc = wp + (size_t)B * N * 3;          // B*27*3 floats

    bnl_prep<<<32, 256, 0, stream>>>(pos, cell, wp, sc, B, N);

    int off = (N / 2) * 3 + 81;
    off = (off + 3) & ~3;
    size_t lds_bytes = ((size_t)off + 256 * 12) * sizeof(float);
    bnl_fill4<<<B * N * 2, 256, lds_bytes, stream>>>(wp, sc, (float*)d_out, B, N);
}